// Round 18
// baseline (273.011 us; speedup 1.0000x reference)
//
#include <hip/hip_runtime.h>
#include <hip/hip_bf16.h>

// ---------------- problem constants ----------------
#define B_N   8
#define S_N   4096
#define D_N   256          // DQK == DV
#define QBLK  128          // q rows per block: 4 waves x 32 rows
#define KVBLK 32           // keys per sub-chunk (compute granule)
#define NCH   (S_N / KVBLK)    // 128 chunks per batch
#define IMGSZ 16384            // bytes per K or V chunk image
// Q prepass scale: 1/sqrt(256) * log2(e)  -> softmax in exp2 domain
#define SCALE_Q (0.0625f * 1.4426950408889634f)

typedef __attribute__((ext_vector_type(8)))  short bf16x8;
typedef __attribute__((ext_vector_type(16))) float f32x16;

// ---------------- async global->LDS (16B/lane, wave-uniform LDS base) -------
__device__ __forceinline__ void async16(const char* g, char* l) {
  __builtin_amdgcn_global_load_lds(
      (const __attribute__((address_space(1))) void*)g,
      (__attribute__((address_space(3))) void*)l, 16, 0, 0);
}

__device__ __forceinline__ unsigned cvt_pk_bf16(float lo, float hi) {
  unsigned r;
  asm("v_cvt_pk_bf16_f32 %0, %1, %2" : "=v"(r) : "v"(lo), "v"(hi));
  return r;
}
__device__ __forceinline__ void swap32(unsigned& a, unsigned& b) {
  asm("v_permlane32_swap_b32 %0, %1" : "+v"(a), "+v"(b));
}
__device__ __forceinline__ float xhalf_max(float x) {
  float a = x, b = x;
  asm("" : "+v"(b));                    // keep a,b in distinct regs (r2 bug)
  asm("v_permlane32_swap_b32 %0, %1" : "+v"(a), "+v"(b));
  return fmaxf(a, b);
}
__device__ __forceinline__ float xhalf_add(float x) {
  float a = x, b = x;
  asm("" : "+v"(b));
  asm("v_permlane32_swap_b32 %0, %1" : "+v"(a), "+v"(b));
  return a + b;
}
// raw v_exp_f32: 2^x
__device__ __forceinline__ float exp2_fast(float x) {
  float r;
  asm("v_exp_f32 %0, %1" : "=v"(r) : "v"(x));
  return r;
}
// bf16 bits of a float (RN) without relying on __hip_bfloat16 internals
__device__ __forceinline__ unsigned short bf16_bits(float x) {
  union { __hip_bfloat16 h; unsigned short u; } cvt;
  cvt.h = __float2bfloat16(x);
  return cvt.u;
}

// ---------------- prepass: NCHW -> (B,S,D) bf16 with pos add (+scale) -------
__global__ void prep_qk(const float* __restrict__ src, const float* __restrict__ pos,
                        __hip_bfloat16* __restrict__ dst, float mul) {
  __shared__ float tile[64][65];
  const int b  = blockIdx.z;
  const int s0 = blockIdx.x * 64;
  const int c0 = blockIdx.y * 64;
  const int t  = threadIdx.x;
  const int x  = t & 63;
  const int y4 = t >> 6;
  const float* sp = src + ((size_t)b * D_N + c0) * S_N + s0;
#pragma unroll
  for (int i = 0; i < 16; ++i) {
    int c = y4 + i * 4;
    tile[c][x] = sp[(size_t)c * S_N + x];
  }
  __syncthreads();
  __hip_bfloat16* dp = dst + ((size_t)b * S_N + s0) * D_N + c0;
  const float* pp = pos + (size_t)s0 * D_N + c0;
#pragma unroll
  for (int i = 0; i < 16; ++i) {
    int s = y4 + i * 4;
    float v = (tile[x][s] + pp[(size_t)s * D_N + x]) * mul;
    dp[(size_t)s * D_N + x] = __float2bfloat16(v);
  }
}

// K -> per-chunk image, k-chunk-major: img[kc][key][32B]
__global__ void prep_kimg(const float* __restrict__ src, const float* __restrict__ pos,
                          char* __restrict__ img) {
  __shared__ float tile[64][65];
  const int b  = blockIdx.z;
  const int s0 = blockIdx.x * 64;
  const int c0 = blockIdx.y * 64;
  const int t  = threadIdx.x;
  const int x  = t & 63;
  const int y4 = t >> 6;
  const float* sp = src + ((size_t)b * D_N + c0) * S_N + s0;
#pragma unroll
  for (int i = 0; i < 16; ++i) {
    int c = y4 + i * 4;
    tile[c][x] = sp[(size_t)c * S_N + x];
  }
  __syncthreads();
  const float* pp = pos + (size_t)s0 * D_N + c0;
#pragma unroll
  for (int i = 0; i < 16; ++i) {
    int srow = y4 + i * 4;
    int d    = c0 + x;
    float v  = tile[x][srow] + pp[(size_t)srow * D_N + x];
    int s    = s0 + srow;
    int ch   = s >> 5;
    char* dst = img + ((size_t)(b * NCH + ch)) * IMGSZ
                + (d >> 4) * 1024 + (s & 31) * 32 + (d & 15) * 2;
    *reinterpret_cast<__hip_bfloat16*>(dst) = __float2bfloat16(v);
  }
}

// V -> per-chunk image, key-chunk-major: img[kf][d][32B]
struct alignas(16) bf8s { __hip_bfloat16 v[8]; };
__global__ void prep_vimg(const float* __restrict__ src, char* __restrict__ img) {
  const int ch = blockIdx.x;
  const int b  = blockIdx.y;
  const int t  = threadIdx.x;
  char* ib = img + ((size_t)(b * NCH + ch)) * IMGSZ;
#pragma unroll
  for (int i = 0; i < 4; ++i) {
    int idx = i * 256 + t;               // 1024 x 16B granules
    int kf  = idx >> 9;                  // 16-key half
    int d   = (idx >> 1) & 255;
    int hf  = idx & 1;                   // 8-key quarter within half
    const float* vs = src + ((size_t)b * D_N + d) * S_N + ch * KVBLK + kf * 16 + hf * 8;
    float4 a = *reinterpret_cast<const float4*>(vs);
    float4 c = *reinterpret_cast<const float4*>(vs + 4);
    bf8s w;
    w.v[0] = __float2bfloat16(a.x); w.v[1] = __float2bfloat16(a.y);
    w.v[2] = __float2bfloat16(a.z); w.v[3] = __float2bfloat16(a.w);
    w.v[4] = __float2bfloat16(c.x); w.v[5] = __float2bfloat16(c.y);
    w.v[6] = __float2bfloat16(c.z); w.v[7] = __float2bfloat16(c.w);
    *reinterpret_cast<bf8s*>(ib + kf * 8192 + d * 32 + hf * 16) = w;
  }
}

// ---- flash attention partial: K via LDS-DMA, V DIRECT from L2 images -------
// LDS (32768 B): [0,16K) K img 2t | [16K,32K) K img 2t+1  (single buffer)
// V fragments are wave-contiguous 1KB reads from the global V image -> plain
// coalesced VMEM loads, L1-dedup'd across the 4 waves; staged bytes halve.
#define LDS_BYTES 32768

__global__ __launch_bounds__(256, 2) void attn_kernel(
    const __hip_bfloat16* __restrict__ Qb, const char* __restrict__ Kt,
    const char* __restrict__ Vt, __hip_bfloat16* __restrict__ P0,
    float2* __restrict__ mlbuf, float* __restrict__ out) {
  __shared__ __align__(16) char lds[LDS_BYTES];

  const int tid  = threadIdx.x;
  const int wave = tid >> 6;
  const int lane = tid & 63;
  const int l31  = lane & 31;
  const int h    = lane >> 5;
  const int lofs = l31 * 32 + h * 16;    // per-lane base offset (K-LDS and V-img)

  // XCD swizzle: hw block i -> XCD i%8; all of batch b on XCD b (KV img = 4MB = L2)
  const int lin = blockIdx.x;            // 0..511
  const int b   = lin & 7;
  const int kvh = (lin >> 3) & 1;        // KV half
  const int qt  = lin >> 4;              // 0..31
  const int q0  = qt * QBLK + wave * 32;
  const int t0  = kvh * (NCH / 2);       // first 32-key chunk of this half

  // ---- Q fragments resident (B-operand: col=l31=q, k = kc*16 + h*8 + j) ----
  bf16x8 qf[16];
  {
    const __hip_bfloat16* qp = Qb + ((size_t)b * S_N + q0 + l31) * D_N + h * 8;
#pragma unroll
    for (int kc = 0; kc < 16; ++kc)
      qf[kc] = *reinterpret_cast<const bf16x8*>(qp + kc * 16);
  }

  // ---- accumulators ----
  f32x16 o[8];
#pragma unroll
  for (int df = 0; df < 8; ++df)
#pragma unroll
    for (int r = 0; r < 16; ++r) o[df][r] = 0.f;
  float m_ = -1e30f, l_ = 0.f;

  const char* kimgB = Kt + (size_t)b * NCH * IMGSZ;
  const char* vimgB = Vt + (size_t)b * NCH * IMGSZ;

  // one 32-key compute body; K from LDS, V direct from global image
  auto COMPUTE = [&](const char* Kbase, const char* vg) {
    // ---- QK^T (swapped): S^T[key][q] = mfma(A=K, B=Q) ----
    f32x16 se;
#pragma unroll
    for (int r = 0; r < 16; ++r) se[r] = 0.f;
    {
      const char* kr = Kbase + lofs;
      __builtin_amdgcn_s_setprio(1);
#pragma unroll
      for (int kc = 0; kc < 16; ++kc) {
        bf16x8 kf8 = *reinterpret_cast<const bf16x8*>(kr + kc * 1024);
        se = __builtin_amdgcn_mfma_f32_32x32x16_bf16(kf8, qf[kc], se, 0, 0, 0);
      }
      __builtin_amdgcn_s_setprio(0);
    }

    // ---- online softmax, exp2 domain (lane-local + one cross-half combine) --
    float t8[8];
#pragma unroll
    for (int i = 0; i < 8; ++i) t8[i] = fmaxf(se[i], se[i + 8]);
    float pm = fmaxf(fmaxf(fmaxf(t8[0], t8[1]), fmaxf(t8[2], t8[3])),
                     fmaxf(fmaxf(t8[4], t8[5]), fmaxf(t8[6], t8[7])));
    float pmax = xhalf_max(pm);

    if (!__all(pmax <= m_ + 11.54f)) {   // defer-max (8*log2e in exp2 domain)
      float mn = fmaxf(m_, pmax);
      float al = exp2_fast(m_ - mn);
      m_ = mn;
      l_ *= al;
#pragma unroll
      for (int df = 0; df < 8; ++df)
#pragma unroll
        for (int r = 0; r < 16; ++r) o[df][r] *= al;
    }
#pragma unroll
    for (int r = 0; r < 16; ++r) se[r] = exp2_fast(se[r] - m_);
    float s8[8];
#pragma unroll
    for (int i = 0; i < 8; ++i) s8[i] = se[i] + se[i + 8];
    float rs = ((s8[0] + s8[1]) + (s8[2] + s8[3])) + ((s8[4] + s8[5]) + (s8[6] + s8[7]));
    l_ += xhalf_add(rs);

    // ---- P -> bf16 B-fragments in-register (verified repack) ----
    union U8 { unsigned u[4]; bf16x8 v; };
    U8 pb[2];
    {
      unsigned u0 = cvt_pk_bf16(se[0],  se[1]);
      unsigned v0 = cvt_pk_bf16(se[4],  se[5]);
      swap32(u0, v0);
      unsigned u1 = cvt_pk_bf16(se[2],  se[3]);
      unsigned v1 = cvt_pk_bf16(se[6],  se[7]);
      swap32(u1, v1);
      pb[0].u[0] = u0; pb[0].u[1] = u1; pb[0].u[2] = v0; pb[0].u[3] = v1;
      unsigned u2 = cvt_pk_bf16(se[8],  se[9]);
      unsigned v2 = cvt_pk_bf16(se[12], se[13]);
      swap32(u2, v2);
      unsigned u3 = cvt_pk_bf16(se[10], se[11]);
      unsigned v3 = cvt_pk_bf16(se[14], se[15]);
      swap32(u3, v3);
      pb[1].u[0] = u2; pb[1].u[1] = u3; pb[1].u[2] = v2; pb[1].u[3] = v3;
    }

    // ---- PV (swapped): O^T[d][q] += mfma(A=V^T direct-from-L2, B=P) ----
    {
      const char* vr = vg + lofs;        // wave reads contiguous 1KB per frag
#pragma unroll
      for (int df = 0; df < 8; ++df) {
        bf16x8 vf0 = *reinterpret_cast<const bf16x8*>(vr + df * 1024);
        bf16x8 vf1 = *reinterpret_cast<const bf16x8*>(vr + 8192 + df * 1024);
        o[df] = __builtin_amdgcn_mfma_f32_32x32x16_bf16(vf0, pb[0].v, o[df], 0, 0, 0);
        o[df] = __builtin_amdgcn_mfma_f32_32x32x16_bf16(vf1, pb[1].v, o[df], 0, 0, 0);
      }
    }
  };

  for (int t = 0; t < NCH / 4; ++t) {    // 32 iterations, 64 keys each
    __syncthreads();                     // previous phase's K fully consumed
    {
      // stage K imgs for chunks 2t, 2t+1 (contiguous 32KB); 8 segs per wave
      const char* s = kimgB + (size_t)(t0 + 2 * t) * IMGSZ;
#pragma unroll
      for (int c = 0; c < 8; ++c) {
        int seg = wave * 8 + c;
        async16(s + seg * 1024 + lane * 16, lds + seg * 1024);
      }
    }
    __syncthreads();                     // staged K visible (vmcnt drained)

    COMPUTE(lds,         vimgB + (size_t)(t0 + 2 * t)     * IMGSZ);
    COMPUTE(lds + 16384, vimgB + (size_t)(t0 + 2 * t + 1) * IMGSZ);
  }

  // ---- epilogue: publish (m,l) and UNNORMALIZED partial O^T ----
  if (h == 0)
    mlbuf[(size_t)(kvh * B_N + b) * S_N + q0 + l31] = make_float2(m_, l_);
  if (kvh) {
    float* pdst = out + (size_t)b * D_N * S_N + q0 + l31;
#pragma unroll
    for (int df = 0; df < 8; ++df)
#pragma unroll
      for (int r = 0; r < 16; ++r) {
        int d = df * 32 + (r & 3) + 8 * (r >> 2) + 4 * h;
        __builtin_nontemporal_store(o[df][r], pdst + (size_t)d * S_N);
      }
  } else {
    unsigned short* pdst = reinterpret_cast<unsigned short*>(P0)
                           + (size_t)b * D_N * S_N + q0 + l31;
#pragma unroll
    for (int df = 0; df < 8; ++df)
#pragma unroll
      for (int r = 0; r < 16; ++r) {
        int d = df * 32 + (r & 3) + 8 * (r >> 2) + 4 * h;
        __builtin_nontemporal_store(bf16_bits(o[df][r]), pdst + (size_t)d * S_N);
      }
  }
}

// ---- fused merge: out = (c0*P0 + c1*P1) / (c0*l0 + c1*l1), exp2 domain -----
__global__ void merge_o(const __hip_bfloat16* __restrict__ P0,
                        const float2* __restrict__ mlbuf, float* __restrict__ out) {
  int i = blockIdx.x * 256 + threadIdx.x;        // float4 index over (b,d,s)
  ushort4 p0u = reinterpret_cast<const ushort4*>(P0)[i];
  float4 p1 = reinterpret_cast<float4*>(out)[i];
  int b  = i >> 18;                              // D*S/4 = 2^18 per batch
  int s4 = i & (S_N / 4 - 1);
  const float2* ml0 = mlbuf + (size_t)b * S_N + s4 * 4;
  const float2* ml1 = ml0 + (size_t)B_N * S_N;
  union { unsigned short u; __hip_bfloat16 h; } cvt;
  float r[4], p0f[4];
  cvt.u = p0u.x; p0f[0] = __bfloat162float(cvt.h);
  cvt.u = p0u.y; p0f[1] = __bfloat162float(cvt.h);
  cvt.u = p0u.z; p0f[2] = __bfloat162float(cvt.h);
  cvt.u = p0u.w; p0f[3] = __bfloat162float(cvt.h);
  float p1f[4] = {p1.x, p1.y, p1.z, p1.w};
#pragma unroll
  for (int j = 0; j < 4; ++j) {
    float2 a = ml0[j], c = ml1[j];
    float ms = fmaxf(a.x, c.x);
    float c0 = exp2f(a.x - ms), c1 = exp2f(c.x - ms);
    float inv = 1.0f / (c0 * a.y + c1 * c.y);
    r[j] = (c0 * p0f[j] + c1 * p1f[j]) * inv;
  }
  reinterpret_cast<float4*>(out)[i] = make_float4(r[0], r[1], r[2], r[3]);
}

// ---------------- launch ----------------
extern "C" void kernel_launch(void* const* d_in, const int* in_sizes, int n_in,
                              void* d_out, int out_size, void* d_ws, size_t ws_size,
                              hipStream_t stream) {
  const float* queries = (const float*)d_in[0];
  const float* keys    = (const float*)d_in[1];
  const float* values  = (const float*)d_in[2];
  const float* q_pos   = (const float*)d_in[3];
  const float* k_pos   = (const float*)d_in[4];
  float* out = (float*)d_out;

  const size_t per = (size_t)B_N * S_N * D_N;       // elements per tensor
  __hip_bfloat16* Qb = (__hip_bfloat16*)d_ws;       // 16.8 MB
  char*   Kt    = (char*)d_ws + per * 2;            // 16.8 MB K images
  char*   Vt    = Kt + per * 2;                     // 16.8 MB V images
  __hip_bfloat16* P0 = (__hip_bfloat16*)(Vt + per * 2);   // 16.8 MB bf16 partial
  float2* mlbuf = (float2*)((char*)P0 + per * 2);   // 512 KB (m,l) x 2 halves

  prep_qk  <<<dim3(S_N / 64, D_N / 64, B_N), 256, 0, stream>>>(queries, q_pos, Qb, SCALE_Q);
  prep_kimg<<<dim3(S_N / 64, D_N / 64, B_N), 256, 0, stream>>>(keys,    k_pos, Kt);
  prep_vimg<<<dim3(NCH, B_N), 256, 0, stream>>>(values, Vt);
  attn_kernel<<<dim3((S_N / QBLK) * B_N * 2), 256, 0, stream>>>(Qb, Kt, Vt, P0, mlbuf, out);
  merge_o<<<dim3((unsigned)(per / 4 / 256)), 256, 0, stream>>>(P0, mlbuf, out);
}

// Round 19
// 189.209 us; speedup vs baseline: 1.4429x; 1.4429x over previous
//
#include <hip/hip_runtime.h>
#include <hip/hip_bf16.h>

// ---------------- problem constants ----------------
#define B_N   8
#define S_N   4096
#define D_N   256          // DQK == DV
#define QBLK  128          // q rows per block: 4 waves x 32 rows
#define KVBLK 32           // keys per sub-chunk (compute granule)
#define NCH   (S_N / KVBLK)    // 128 chunks per batch
#define IMGSZ 16384            // bytes per K or V chunk image
// Q prepass scale: 1/sqrt(256) * log2(e)  -> softmax in exp2 domain
#define SCALE_Q (0.0625f * 1.4426950408889634f)

typedef __attribute__((ext_vector_type(8)))  short bf16x8;
typedef __attribute__((ext_vector_type(16))) float f32x16;

// ---------------- async global->LDS (16B/lane, wave-uniform LDS base) -------
__device__ __forceinline__ void async16(const char* g, char* l) {
  __builtin_amdgcn_global_load_lds(
      (const __attribute__((address_space(1))) void*)g,
      (__attribute__((address_space(3))) void*)l, 16, 0, 0);
}

__device__ __forceinline__ unsigned cvt_pk_bf16(float lo, float hi) {
  unsigned r;
  asm("v_cvt_pk_bf16_f32 %0, %1, %2" : "=v"(r) : "v"(lo), "v"(hi));
  return r;
}
__device__ __forceinline__ void swap32(unsigned& a, unsigned& b) {
  asm("v_permlane32_swap_b32 %0, %1" : "+v"(a), "+v"(b));
}
__device__ __forceinline__ float xhalf_max(float x) {
  float a = x, b = x;
  asm("" : "+v"(b));                    // keep a,b in distinct regs (r2 bug)
  asm("v_permlane32_swap_b32 %0, %1" : "+v"(a), "+v"(b));
  return fmaxf(a, b);
}
__device__ __forceinline__ float xhalf_add(float x) {
  float a = x, b = x;
  asm("" : "+v"(b));
  asm("v_permlane32_swap_b32 %0, %1" : "+v"(a), "+v"(b));
  return a + b;
}
// raw v_exp_f32: 2^x
__device__ __forceinline__ float exp2_fast(float x) {
  float r;
  asm("v_exp_f32 %0, %1" : "=v"(r) : "v"(x));
  return r;
}
// bf16 bits of a float (RN) without relying on __hip_bfloat16 internals
__device__ __forceinline__ unsigned short bf16_bits(float x) {
  union { __hip_bfloat16 h; unsigned short u; } cvt;
  cvt.h = __float2bfloat16(x);
  return cvt.u;
}

// ----- fused prepass: Q -> (B,S,D) bf16 (scaled) AND K -> k-chunk images ----
// gridDim.z = 16: z&7 = batch, z>>3 = 0 (Q path) / 1 (K path)
__global__ void prep_qk_kimg(const float* __restrict__ qsrc, const float* __restrict__ qpos,
                             __hip_bfloat16* __restrict__ qdst,
                             const float* __restrict__ ksrc, const float* __restrict__ kpos,
                             char* __restrict__ kimg) {
  __shared__ float tile[64][65];
  const int z  = blockIdx.z;
  const int b  = z & 7;
  const int isK = z >> 3;
  const int s0 = blockIdx.x * 64;
  const int c0 = blockIdx.y * 64;
  const int t  = threadIdx.x;
  const int x  = t & 63;
  const int y4 = t >> 6;
  const float* src = isK ? ksrc : qsrc;
  const float* pos = isK ? kpos : qpos;
  const float* sp = src + ((size_t)b * D_N + c0) * S_N + s0;
#pragma unroll
  for (int i = 0; i < 16; ++i) {
    int c = y4 + i * 4;
    tile[c][x] = sp[(size_t)c * S_N + x];
  }
  __syncthreads();
  const float* pp = pos + (size_t)s0 * D_N + c0;
  if (isK) {
#pragma unroll
    for (int i = 0; i < 16; ++i) {
      int srow = y4 + i * 4;
      int d    = c0 + x;
      float v  = tile[x][srow] + pp[(size_t)srow * D_N + x];
      int s    = s0 + srow;
      int ch   = s >> 5;
      char* dst = kimg + ((size_t)(b * NCH + ch)) * IMGSZ
                  + (d >> 4) * 1024 + (s & 31) * 32 + (d & 15) * 2;
      *reinterpret_cast<__hip_bfloat16*>(dst) = __float2bfloat16(v);
    }
  } else {
    __hip_bfloat16* dp = qdst + ((size_t)b * S_N + s0) * D_N + c0;
#pragma unroll
    for (int i = 0; i < 16; ++i) {
      int s = y4 + i * 4;
      float v = (tile[x][s] + pp[(size_t)s * D_N + x]) * SCALE_Q;
      dp[(size_t)s * D_N + x] = __float2bfloat16(v);
    }
  }
}

// V -> per-chunk image, key-chunk-major: img[kf][d][32B]
struct alignas(16) bf8s { __hip_bfloat16 v[8]; };
__global__ void prep_vimg(const float* __restrict__ src, char* __restrict__ img) {
  const int ch = blockIdx.x;
  const int b  = blockIdx.y;
  const int t  = threadIdx.x;
  char* ib = img + ((size_t)(b * NCH + ch)) * IMGSZ;
#pragma unroll
  for (int i = 0; i < 4; ++i) {
    int idx = i * 256 + t;               // 1024 x 16B granules
    int kf  = idx >> 9;                  // 16-key half
    int d   = (idx >> 1) & 255;
    int hf  = idx & 1;                   // 8-key quarter within half
    const float* vs = src + ((size_t)b * D_N + d) * S_N + ch * KVBLK + kf * 16 + hf * 8;
    float4 a = *reinterpret_cast<const float4*>(vs);
    float4 c = *reinterpret_cast<const float4*>(vs + 4);
    bf8s w;
    w.v[0] = __float2bfloat16(a.x); w.v[1] = __float2bfloat16(a.y);
    w.v[2] = __float2bfloat16(a.z); w.v[3] = __float2bfloat16(a.w);
    w.v[4] = __float2bfloat16(c.x); w.v[5] = __float2bfloat16(c.y);
    w.v[6] = __float2bfloat16(c.z); w.v[7] = __float2bfloat16(c.w);
    *reinterpret_cast<bf8s*>(ib + kf * 8192 + d * 32 + hf * 16) = w;
  }
}

// ---- flash attention partial: QBLK=128, split-KV x2, 64-key stage phases ---
// (r17-verified structure: K AND V staged via LDS-DMA, full-drain phases)
// LDS (65536 B): [0,16K) K img 2t | [16K,32K) K img 2t+1
//                [32K,48K) V img 2t | [48K,64K) V img 2t+1
#define LDS_BYTES 65536

__global__ __launch_bounds__(256, 2) void attn_kernel(
    const __hip_bfloat16* __restrict__ Qb, const char* __restrict__ Kt,
    const char* __restrict__ Vt, __hip_bfloat16* __restrict__ P0,
    __hip_bfloat16* __restrict__ P1, float2* __restrict__ mlbuf) {
  __shared__ __align__(16) char lds[LDS_BYTES];

  const int tid  = threadIdx.x;
  const int wave = tid >> 6;
  const int lane = tid & 63;
  const int l31  = lane & 31;
  const int h    = lane >> 5;
  const int lofs = l31 * 32 + h * 16;    // per-lane LDS base offset (K and V)

  // XCD swizzle: hw block i -> XCD i%8; all of batch b on XCD b (KV img = 4MB = L2)
  const int lin = blockIdx.x;            // 0..511
  const int b   = lin & 7;
  const int kvh = (lin >> 3) & 1;        // KV half
  const int qt  = lin >> 4;              // 0..31
  const int q0  = qt * QBLK + wave * 32;
  const int t0  = kvh * (NCH / 2);       // first 32-key chunk of this half

  // ---- Q fragments resident (B-operand: col=l31=q, k = kc*16 + h*8 + j) ----
  bf16x8 qf[16];
  {
    const __hip_bfloat16* qp = Qb + ((size_t)b * S_N + q0 + l31) * D_N + h * 8;
#pragma unroll
    for (int kc = 0; kc < 16; ++kc)
      qf[kc] = *reinterpret_cast<const bf16x8*>(qp + kc * 16);
  }

  // ---- accumulators ----
  f32x16 o[8];
#pragma unroll
  for (int df = 0; df < 8; ++df)
#pragma unroll
    for (int r = 0; r < 16; ++r) o[df][r] = 0.f;
  float m_ = -1e30f, l_ = 0.f;

  const char* kimgB = Kt + (size_t)b * NCH * IMGSZ;
  const char* vimgB = Vt + (size_t)b * NCH * IMGSZ;

  // one 32-key compute body (exp2 domain; linear-immediate LDS addressing)
  auto COMPUTE = [&](const char* Kbase, const char* Vbase) {
    // ---- QK^T (swapped): S^T[key][q] = mfma(A=K, B=Q) ----
    f32x16 se;
#pragma unroll
    for (int r = 0; r < 16; ++r) se[r] = 0.f;
    {
      const char* kr = Kbase + lofs;
      __builtin_amdgcn_s_setprio(1);
#pragma unroll
      for (int kc = 0; kc < 16; ++kc) {
        bf16x8 kf8 = *reinterpret_cast<const bf16x8*>(kr + kc * 1024);
        se = __builtin_amdgcn_mfma_f32_32x32x16_bf16(kf8, qf[kc], se, 0, 0, 0);
      }
      __builtin_amdgcn_s_setprio(0);
    }

    // ---- online softmax, exp2 domain (lane-local + one cross-half combine) --
    float t8[8];
#pragma unroll
    for (int i = 0; i < 8; ++i) t8[i] = fmaxf(se[i], se[i + 8]);
    float pm = fmaxf(fmaxf(fmaxf(t8[0], t8[1]), fmaxf(t8[2], t8[3])),
                     fmaxf(fmaxf(t8[4], t8[5]), fmaxf(t8[6], t8[7])));
    float pmax = xhalf_max(pm);

    if (!__all(pmax <= m_ + 11.54f)) {   // defer-max (8*log2e in exp2 domain)
      float mn = fmaxf(m_, pmax);
      float al = exp2_fast(m_ - mn);
      m_ = mn;
      l_ *= al;
#pragma unroll
      for (int df = 0; df < 8; ++df)
#pragma unroll
        for (int r = 0; r < 16; ++r) o[df][r] *= al;
    }
#pragma unroll
    for (int r = 0; r < 16; ++r) se[r] = exp2_fast(se[r] - m_);
    float s8[8];
#pragma unroll
    for (int i = 0; i < 8; ++i) s8[i] = se[i] + se[i + 8];
    float rs = ((s8[0] + s8[1]) + (s8[2] + s8[3])) + ((s8[4] + s8[5]) + (s8[6] + s8[7]));
    l_ += xhalf_add(rs);

    // ---- P -> bf16 B-fragments in-register (verified repack) ----
    union U8 { unsigned u[4]; bf16x8 v; };
    U8 pb[2];
    {
      unsigned u0 = cvt_pk_bf16(se[0],  se[1]);
      unsigned v0 = cvt_pk_bf16(se[4],  se[5]);
      swap32(u0, v0);
      unsigned u1 = cvt_pk_bf16(se[2],  se[3]);
      unsigned v1 = cvt_pk_bf16(se[6],  se[7]);
      swap32(u1, v1);
      pb[0].u[0] = u0; pb[0].u[1] = u1; pb[0].u[2] = v0; pb[0].u[3] = v1;
      unsigned u2 = cvt_pk_bf16(se[8],  se[9]);
      unsigned v2 = cvt_pk_bf16(se[12], se[13]);
      swap32(u2, v2);
      unsigned u3 = cvt_pk_bf16(se[10], se[11]);
      unsigned v3 = cvt_pk_bf16(se[14], se[15]);
      swap32(u3, v3);
      pb[1].u[0] = u2; pb[1].u[1] = u3; pb[1].u[2] = v2; pb[1].u[3] = v3;
    }

    // ---- PV (swapped): O^T[d][q] += mfma(A=V^T, B=P) ----
    {
      const char* vr = Vbase + lofs;
      __builtin_amdgcn_s_setprio(1);
#pragma unroll
      for (int df = 0; df < 8; ++df) {
        bf16x8 vf0 = *reinterpret_cast<const bf16x8*>(vr + df * 1024);
        bf16x8 vf1 = *reinterpret_cast<const bf16x8*>(vr + 8192 + df * 1024);
        o[df] = __builtin_amdgcn_mfma_f32_32x32x16_bf16(vf0, pb[0].v, o[df], 0, 0, 0);
        o[df] = __builtin_amdgcn_mfma_f32_32x32x16_bf16(vf1, pb[1].v, o[df], 0, 0, 0);
      }
      __builtin_amdgcn_s_setprio(0);
    }
  };

  for (int t = 0; t < NCH / 4; ++t) {    // 32 iterations, 64 keys each
    __syncthreads();                     // previous phase fully consumed
    {
      // wave 0 -> K img 2t, wave 1 -> K img 2t+1, wave 2 -> V img 2t,
      // wave 3 -> V img 2t+1; each a pure linear 16KB copy
      const int ch = t0 + 2 * t + (wave & 1);
      const char* s = (wave < 2 ? kimgB : vimgB) + (size_t)ch * IMGSZ;
      char* dstb = lds + (wave < 2 ? 0 : 32768) + (wave & 1) * 16384;
#pragma unroll
      for (int c = 0; c < 16; ++c)
        async16(s + c * 1024 + lane * 16, dstb + c * 1024);
    }
    __syncthreads();                     // staged data visible (vmcnt drained)

    COMPUTE(lds,         lds + 32768);   // keys [64t, 64t+32)
    COMPUTE(lds + 16384, lds + 49152);   // keys [64t+32, 64t+64)
  }

  // ---- epilogue: publish (m,l) and UNNORMALIZED bf16 partial O^T ----
  if (h == 0)
    mlbuf[(size_t)(kvh * B_N + b) * S_N + q0 + l31] = make_float2(m_, l_);
  unsigned short* pdst = reinterpret_cast<unsigned short*>(kvh ? P1 : P0)
                         + (size_t)b * D_N * S_N + q0 + l31;
#pragma unroll
  for (int df = 0; df < 8; ++df)
#pragma unroll
    for (int r = 0; r < 16; ++r) {
      int d = df * 32 + (r & 3) + 8 * (r >> 2) + 4 * h;
      __builtin_nontemporal_store(bf16_bits(o[df][r]), pdst + (size_t)d * S_N);
    }
}

// ---- fused merge: out = (c0*P0 + c1*P1) / (c0*l0 + c1*l1), exp2 domain -----
__global__ void merge_o(const __hip_bfloat16* __restrict__ P0,
                        const __hip_bfloat16* __restrict__ P1,
                        const float2* __restrict__ mlbuf, float* __restrict__ out) {
  int i = blockIdx.x * 256 + threadIdx.x;        // float4 index over (b,d,s)
  ushort4 p0u = reinterpret_cast<const ushort4*>(P0)[i];
  ushort4 p1u = reinterpret_cast<const ushort4*>(P1)[i];
  int b  = i >> 18;                              // D*S/4 = 2^18 per batch
  int s4 = i & (S_N / 4 - 1);
  const float2* ml0 = mlbuf + (size_t)b * S_N + s4 * 4;
  const float2* ml1 = ml0 + (size_t)B_N * S_N;
  union { unsigned short u; __hip_bfloat16 h; } cvt;
  float p0f[4], p1f[4], r[4];
  cvt.u = p0u.x; p0f[0] = __bfloat162float(cvt.h);
  cvt.u = p0u.y; p0f[1] = __bfloat162float(cvt.h);
  cvt.u = p0u.z; p0f[2] = __bfloat162float(cvt.h);
  cvt.u = p0u.w; p0f[3] = __bfloat162float(cvt.h);
  cvt.u = p1u.x; p1f[0] = __bfloat162float(cvt.h);
  cvt.u = p1u.y; p1f[1] = __bfloat162float(cvt.h);
  cvt.u = p1u.z; p1f[2] = __bfloat162float(cvt.h);
  cvt.u = p1u.w; p1f[3] = __bfloat162float(cvt.h);
#pragma unroll
  for (int j = 0; j < 4; ++j) {
    float2 a = ml0[j], c = ml1[j];
    float ms = fmaxf(a.x, c.x);
    float c0 = exp2f(a.x - ms), c1 = exp2f(c.x - ms);
    float inv = 1.0f / (c0 * a.y + c1 * c.y);
    r[j] = (c0 * p0f[j] + c1 * p1f[j]) * inv;
  }
  reinterpret_cast<float4*>(out)[i] = make_float4(r[0], r[1], r[2], r[3]);
}

// ---------------- launch ----------------
extern "C" void kernel_launch(void* const* d_in, const int* in_sizes, int n_in,
                              void* d_out, int out_size, void* d_ws, size_t ws_size,
                              hipStream_t stream) {
  const float* queries = (const float*)d_in[0];
  const float* keys    = (const float*)d_in[1];
  const float* values  = (const float*)d_in[2];
  const float* q_pos   = (const float*)d_in[3];
  const float* k_pos   = (const float*)d_in[4];
  float* out = (float*)d_out;

  const size_t per = (size_t)B_N * S_N * D_N;       // elements per tensor
  __hip_bfloat16* Qb = (__hip_bfloat16*)d_ws;       // 16.8 MB
  char* Kt = (char*)d_ws + per * 2;                 // 16.8 MB K images
  char* Vt = Kt + per * 2;                          // 16.8 MB V images
  __hip_bfloat16* P0 = (__hip_bfloat16*)(Vt + per * 2);   // 16.8 MB bf16 partial 0
  __hip_bfloat16* P1 = P0 + per;                    // 16.8 MB bf16 partial 1
  float2* mlbuf = (float2*)(P1 + per);              // 512 KB (m,l) x 2 halves

  prep_qk_kimg<<<dim3(S_N / 64, D_N / 64, 2 * B_N), 256, 0, stream>>>(
      queries, q_pos, Qb, keys, k_pos, Kt);
  prep_vimg<<<dim3(NCH, B_N), 256, 0, stream>>>(values, Vt);
  attn_kernel<<<dim3((S_N / QBLK) * B_N * 2), 256, 0, stream>>>(Qb, Kt, Vt, P0, P1, mlbuf);
  merge_o<<<dim3((unsigned)(per / 4 / 256)), 256, 0, stream>>>(P0, P1, mlbuf, out);
}